// Round 1
// baseline (224.459 us; speedup 1.0000x reference)
//
#include <hip/hip_runtime.h>
#include <hip/hip_bf16.h>

// TTT kernel: out = tril((2Q - tril(Q K^T) K) K^T) V, per (b,h).
// Two fused causal passes of Y = tril(X K^T) W  (pass1: X=Q,W=K -> o2;
// pass2: X=2Q-o2, W=V -> out). bf16 MFMA 16x16x32, fp32 accum.

typedef __bf16 bf16x8 __attribute__((ext_vector_type(8)));
typedef float  f32x4  __attribute__((ext_vector_type(4)));

#define MFMA16(a, b, c) __builtin_amdgcn_mfma_f32_16x16x32_bf16((a), (b), (c), 0, 0, 0)

static constexpr int S    = 2048;
static constexpr int H    = 16;
static constexpr int D    = 64;
static constexpr int RS   = 3 * H * D;  // 3072 floats between consecutive s rows
static constexpr int BM   = 128;        // query rows per workgroup
static constexpr int BN   = 64;         // key rows per iteration
static constexpr int LROW = 72;         // 64 + 8 pad (16B) -> b128-aligned, conflict-safe

__global__ __launch_bounds__(256, 2)
void ttt_kernel(const float* __restrict__ qkv, float* __restrict__ out)
{
    __shared__ __bf16 ldsX[BM * LROW];      // X tile, row-major [t][d]
    __shared__ __bf16 ldsK[BN * LROW];      // K tile, row-major [s][d]
    __shared__ __bf16 ldsW[D  * LROW];      // W tile, transposed [d][s]
    __shared__ __bf16 ldsP[4 * 32 * LROW];  // per-wave P [32][64+pad]

    const int tid  = threadIdx.x;
    const int wv   = tid >> 6;
    const int lane = tid & 63;
    const int quad = lane >> 4;   // 0..3
    const int l16  = lane & 15;

    const int ti = 15 - (int)blockIdx.x;    // heavy (large-ti) blocks dispatch first
    const int bh = (int)blockIdx.y;
    const int b  = bh >> 4;
    const int h  = bh & 15;
    const int t0 = ti * BM;
    const int nSB = 2 * ti + 2;             // causal: key blocks sb*64 <= t0+BM-1

    const float* baseQ = qkv + (size_t)b * S * RS + h * D;
    const float* baseK = baseQ + H * D;
    const float* baseV = baseQ + 2 * H * D;

    // ---- stage X = Q rows [t0, t0+128) -> ldsX (bf16, row-major) ----
    {
        const int r  = tid >> 1;
        const int cb = (tid & 1) * 32;
        const float* p = baseQ + (size_t)(t0 + r) * RS + cb;
        __bf16* dst = ldsX + r * LROW + cb;
#pragma unroll
        for (int u = 0; u < 4; ++u) {
            f32x4 f0 = *(const f32x4*)(p + u * 8);
            f32x4 f1 = *(const f32x4*)(p + u * 8 + 4);
            bf16x8 w;
            w[0] = (__bf16)f0[0]; w[1] = (__bf16)f0[1];
            w[2] = (__bf16)f0[2]; w[3] = (__bf16)f0[3];
            w[4] = (__bf16)f1[0]; w[5] = (__bf16)f1[1];
            w[6] = (__bf16)f1[2]; w[7] = (__bf16)f1[3];
            *(bf16x8*)(dst + u * 8) = w;
        }
    }

    // stage one 64x64 fp32 tile (rows [s0,s0+64)) into row-major and/or transposed LDS
    auto stage64 = [&](const float* src, int s0, __bf16* rowm, __bf16* transp) {
        const int r  = tid >> 2;
        const int cb = (tid & 3) * 16;
        const float* p = src + (size_t)(s0 + r) * RS + cb;
        __bf16 c[16];
#pragma unroll
        for (int u = 0; u < 4; ++u) {
            f32x4 f = *(const f32x4*)(p + u * 4);
            c[u * 4 + 0] = (__bf16)f[0]; c[u * 4 + 1] = (__bf16)f[1];
            c[u * 4 + 2] = (__bf16)f[2]; c[u * 4 + 3] = (__bf16)f[3];
        }
        if (rowm) {
            bf16x8 w0, w1;
#pragma unroll
            for (int j = 0; j < 8; ++j) { w0[j] = c[j]; w1[j] = c[8 + j]; }
            *(bf16x8*)(rowm + r * LROW + cb)     = w0;
            *(bf16x8*)(rowm + r * LROW + cb + 8) = w1;
        }
        if (transp) {
#pragma unroll
            for (int j = 0; j < 16; ++j) transp[(cb + j) * LROW + r] = c[j];
        }
    };

    const f32x4 zero4 = {0.0f, 0.0f, 0.0f, 0.0f};
    f32x4 Y[2][4];
    __bf16* myP = ldsP + wv * 32 * LROW;

    for (int pass = 0; pass < 2; ++pass) {
#pragma unroll
        for (int mi = 0; mi < 2; ++mi)
#pragma unroll
            for (int ni = 0; ni < 4; ++ni) Y[mi][ni] = zero4;

        for (int sb = 0; sb < nSB; ++sb) {
            if (pass == 0) {
                stage64(baseK, sb * BN, ldsK, ldsW);            // W = K
            } else {
                stage64(baseK, sb * BN, ldsK, nullptr);
                stage64(baseV, sb * BN, nullptr, ldsW);         // W = V
            }
            __syncthreads();

            // ---- GEMM1: P[t][s] = sum_d X[t][d] K[s][d] ----
            f32x4 P[2][4];
#pragma unroll
            for (int mi = 0; mi < 2; ++mi)
#pragma unroll
                for (int ni = 0; ni < 4; ++ni) P[mi][ni] = zero4;
#pragma unroll
            for (int ks = 0; ks < 2; ++ks) {
                bf16x8 a0 = *(bf16x8*)(ldsX + (wv * 32 + l16) * LROW + ks * 32 + quad * 8);
                bf16x8 a1 = *(bf16x8*)(ldsX + (wv * 32 + 16 + l16) * LROW + ks * 32 + quad * 8);
#pragma unroll
                for (int ni = 0; ni < 4; ++ni) {
                    bf16x8 bf = *(bf16x8*)(ldsK + (ni * 16 + l16) * LROW + ks * 32 + quad * 8);
                    P[0][ni] = MFMA16(a0, bf, P[0][ni]);
                    P[1][ni] = MFMA16(a1, bf, P[1][ni]);
                }
            }

            // ---- causal mask + C-layout -> LDS (wave-private) ----
#pragma unroll
            for (int mi = 0; mi < 2; ++mi) {
                const int tg = t0 + wv * 32 + mi * 16 + quad * 4;  // + r = global t
#pragma unroll
                for (int ni = 0; ni < 4; ++ni) {
                    const int sg = sb * BN + ni * 16 + l16;        // global s
#pragma unroll
                    for (int r = 0; r < 4; ++r) {
                        float val = (sg <= tg + r) ? P[mi][ni][r] : 0.0f;
                        myP[(mi * 16 + quad * 4 + r) * LROW + ni * 16 + l16] = (__bf16)val;
                    }
                }
            }

            // ---- GEMM2: Y[t][d] += sum_s P[t][s] W[s][d]  (ldsW = W^T) ----
#pragma unroll
            for (int ks = 0; ks < 2; ++ks) {
                bf16x8 a0 = *(bf16x8*)(myP + (l16) * LROW + ks * 32 + quad * 8);
                bf16x8 a1 = *(bf16x8*)(myP + (16 + l16) * LROW + ks * 32 + quad * 8);
#pragma unroll
                for (int ni = 0; ni < 4; ++ni) {
                    bf16x8 bf = *(bf16x8*)(ldsW + (ni * 16 + l16) * LROW + ks * 32 + quad * 8);
                    Y[0][ni] = MFMA16(a0, bf, Y[0][ni]);
                    Y[1][ni] = MFMA16(a1, bf, Y[1][ni]);
                }
            }
            __syncthreads();   // before next iteration restages ldsK/ldsW
        }

        if (pass == 0) {
            // X2 = 2Q - o2, written into ldsX (each lane owns its (t,d) elements)
#pragma unroll
            for (int mi = 0; mi < 2; ++mi)
#pragma unroll
                for (int ni = 0; ni < 4; ++ni)
#pragma unroll
                    for (int r = 0; r < 4; ++r) {
                        const int tl = wv * 32 + mi * 16 + quad * 4 + r;
                        const int d  = ni * 16 + l16;
                        float qv = (float)ldsX[tl * LROW + d];
                        ldsX[tl * LROW + d] = (__bf16)(2.0f * qv - Y[mi][ni][r]);
                    }
            // next pass's first __syncthreads (after staging) orders this vs GEMM1 reads
        } else {
            // out[b][t][h][d], fp32
#pragma unroll
            for (int mi = 0; mi < 2; ++mi)
#pragma unroll
                for (int ni = 0; ni < 4; ++ni)
#pragma unroll
                    for (int r = 0; r < 4; ++r) {
                        const int t = t0 + wv * 32 + mi * 16 + quad * 4 + r;
                        const int d = ni * 16 + l16;
                        out[(((size_t)b * S + t) * H + h) * D + d] = Y[mi][ni][r];
                    }
        }
    }
}

extern "C" void kernel_launch(void* const* d_in, const int* in_sizes, int n_in,
                              void* d_out, int out_size, void* d_ws, size_t ws_size,
                              hipStream_t stream)
{
    const float* qkv = (const float*)d_in[0];
    float* out = (float*)d_out;
    dim3 grid(S / BM, 2 * H);   // 16 t-blocks x 32 (b,h)
    ttt_kernel<<<grid, 256, 0, stream>>>(qkv, out);
}

// Round 2
// 217.716 us; speedup vs baseline: 1.0310x; 1.0310x over previous
//
#include <hip/hip_runtime.h>
#include <hip/hip_bf16.h>

// out = tril((2Q - tril(QK^T)K) K^T) V per (b,h): two fused causal passes of
// Y = tril(X K^T) W  (pass0: X=Q,W=K -> o2; pass1: X=2Q-o2, W=V).
// R2: P^T formulation (b64 P roundtrip), hoisted X frags, swizzled W^T staging,
// register-prefetch software pipeline. bf16 MFMA 16x16x32, fp32 accum.

typedef __bf16 bf16x8 __attribute__((ext_vector_type(8)));
typedef __bf16 bf16x4 __attribute__((ext_vector_type(4)));
typedef __bf16 bf16x2 __attribute__((ext_vector_type(2)));
typedef float  f32x4  __attribute__((ext_vector_type(4)));

#define MFMA16(a, b, c) __builtin_amdgcn_mfma_f32_16x16x32_bf16((a), (b), (c), 0, 0, 0)

static constexpr int S  = 2048;
static constexpr int H  = 16;
static constexpr int D  = 64;
static constexpr int RS = 3 * H * D;   // 3072 floats between consecutive s rows
static constexpr int BM = 128;         // query rows per workgroup (32/wave)
static constexpr int BN = 64;          // key rows per iteration
static constexpr int LR = 72;          // row stride (u16): 64 + 8 -> 16B-aligned octets

__global__ __launch_bounds__(256, 2)
void ttt_kernel(const float* __restrict__ qkv, float* __restrict__ out)
{
    __shared__ __bf16 ldsP[BM * LR];   // Q staging, then per-wave P / o2 regions
    __shared__ __bf16 ldsK[BN * LR];   // K tile row-major [s][d]
    __shared__ __bf16 ldsW[D  * LR];   // W^T [d][s^swz]

    const int tid  = threadIdx.x;
    const int wv   = tid >> 6;
    const int lane = tid & 63;
    const int q    = lane >> 4;        // quad 0..3
    const int l16  = lane & 15;

    const int ti = 15 - (int)blockIdx.x;     // heavy blocks dispatch first
    const int bh = (int)blockIdx.y;
    const int b  = bh >> 4;
    const int h  = bh & 15;
    const int t0 = ti * BM;
    const int nSB = 2 * ti + 2;

    const float* baseQ = qkv + (size_t)b * S * RS + h * D;
    const float* baseK = baseQ + H * D;
    const float* baseV = baseQ + 2 * H * D;

    // staging coords: thread owns rows r2,r2+1 cols cb..cb+7 of a 64x64 tile
    const int r2 = (tid >> 3) * 2;
    const int cb = (tid & 7) * 8;

    // ---- stage Q rows [t0,t0+128) -> ldsP row-major [t][d] ----
    {
        const int r   = tid >> 1;
        const int cbq = (tid & 1) * 32;
        const float* p = baseQ + (size_t)(t0 + r) * RS + cbq;
        __bf16* dst = ldsP + r * LR + cbq;
#pragma unroll
        for (int u = 0; u < 4; ++u) {
            f32x4 f0 = *(const f32x4*)(p + u * 8);
            f32x4 f1 = *(const f32x4*)(p + u * 8 + 4);
            bf16x8 w;
#pragma unroll
            for (int j = 0; j < 4; ++j) { w[j] = (__bf16)f0[j]; w[4 + j] = (__bf16)f1[j]; }
            *(bf16x8*)(dst + u * 8) = w;
        }
    }

    f32x4 pk[4], pv[4];   // prefetch regs: [0..1]=row r2, [2..3]=row r2+1
    auto loadT = [&](f32x4* dst, const float* base, int s0) {
        const float* p = base + (size_t)(s0 + r2) * RS + cb;
        dst[0] = *(const f32x4*)(p);
        dst[1] = *(const f32x4*)(p + 4);
        dst[2] = *(const f32x4*)(p + RS);
        dst[3] = *(const f32x4*)(p + RS + 4);
    };
    loadT(pk, baseK, 0);

    __syncthreads();   // Q staged

    // ---- hoist X B-frags: Xf[ni][kt], lane holds X[t=l16+16ni][d=kt*32+q*8+j] ----
    bf16x8 Xf[2][2];
    const int myT = wv * 32;
#pragma unroll
    for (int ni = 0; ni < 2; ++ni)
#pragma unroll
        for (int kt = 0; kt < 2; ++kt)
            Xf[ni][kt] = *(bf16x8*)(ldsP + (myT + ni * 16 + l16) * LR + kt * 32 + q * 8);

    __bf16* myP = ldsP + myT * LR;         // wave-private [32][LR]
    const int sw = (l16 & 7) << 3;         // P-region swizzle

    const f32x4 zero4 = {0.f, 0.f, 0.f, 0.f};
    f32x4 Y[2][4];                          // [mt][nd]
#pragma unroll
    for (int mt = 0; mt < 2; ++mt)
#pragma unroll
        for (int nd = 0; nd < 4; ++nd) Y[mt][nd] = zero4;

    for (int pass = 0; pass < 2; ++pass) {
        for (int sb = 0; sb < nSB; ++sb) {
            __syncthreads();   // prior iter's ldsK/ldsW reads done
            // ---- commit prefetched tile to LDS ----
            {
                bf16x8 w0, w1;
#pragma unroll
                for (int j = 0; j < 4; ++j) {
                    w0[j] = (__bf16)pk[0][j]; w0[4 + j] = (__bf16)pk[1][j];
                    w1[j] = (__bf16)pk[2][j]; w1[4 + j] = (__bf16)pk[3][j];
                }
                *(bf16x8*)(ldsK + r2 * LR + cb)       = w0;
                *(bf16x8*)(ldsK + (r2 + 1) * LR + cb) = w1;
                f32x4* src = (pass == 0) ? pk : pv;
#pragma unroll
                for (int j = 0; j < 8; ++j) {
                    const int d = cb + j;
                    const int f = ((d >> 3) ^ d) & 7;
                    bf16x2 w;
                    w[0] = (__bf16)((j < 4) ? src[0][j & 3] : src[1][j & 3]);
                    w[1] = (__bf16)((j < 4) ? src[2][j & 3] : src[3][j & 3]);
                    *(bf16x2*)(ldsW + d * LR + (r2 ^ (f << 3))) = w;
                }
            }
            __syncthreads();   // tile visible

            // ---- prefetch next tile (drains at next barrier, a full iter away) ----
            if (sb + 1 < nSB) {
                loadT(pk, baseK, (sb + 1) * BN);
                if (pass == 1) loadT(pv, baseV, (sb + 1) * BN);
            } else if (pass == 0) {
                loadT(pk, baseK, 0);
                loadT(pv, baseV, 0);
            }

            // ---- GEMM1-T: Pt[s][t] = sum_d K[s][d] X[t][d]  (A=K, B=X^T) ----
            f32x4 Pt[4][2];
#pragma unroll
            for (int mi = 0; mi < 4; ++mi)
#pragma unroll
                for (int ni = 0; ni < 2; ++ni) Pt[mi][ni] = zero4;
#pragma unroll
            for (int kt = 0; kt < 2; ++kt) {
                bf16x8 kf[4];
#pragma unroll
                for (int mi = 0; mi < 4; ++mi)
                    kf[mi] = *(bf16x8*)(ldsK + (mi * 16 + l16) * LR + kt * 32 + q * 8);
#pragma unroll
                for (int mi = 0; mi < 4; ++mi)
#pragma unroll
                    for (int ni = 0; ni < 2; ++ni)
                        Pt[mi][ni] = MFMA16(kf[mi], Xf[ni][kt], Pt[mi][ni]);
            }

            // ---- mask + pack + b64 store: myP[t_local][s^sw] = tril(P)[t][s] ----
#pragma unroll
            for (int mi = 0; mi < 4; ++mi)
#pragma unroll
                for (int ni = 0; ni < 2; ++ni) {
                    const int sgB = sb * BN + mi * 16 + q * 4;
                    const int tg  = t0 + myT + ni * 16 + l16;
                    bf16x4 pw;
#pragma unroll
                    for (int r = 0; r < 4; ++r)
                        pw[r] = (__bf16)((sgB + r <= tg) ? Pt[mi][ni][r] : 0.0f);
                    *(bf16x4*)(myP + (ni * 16 + l16) * LR + ((mi * 16 + q * 4) ^ sw)) = pw;
                }

            // ---- GEMM2: Y[t][d] += sum_s P[t][s] W[s][d] ----
#pragma unroll
            for (int kt = 0; kt < 2; ++kt) {
                bf16x8 af[2];
#pragma unroll
                for (int mt = 0; mt < 2; ++mt)
                    af[mt] = *(bf16x8*)(myP + (mt * 16 + l16) * LR + ((kt * 32 + q * 8) ^ sw));
#pragma unroll
                for (int nd = 0; nd < 4; ++nd) {
                    const int d = l16 + nd * 16;
                    const int f = ((d >> 3) ^ d) & 7;
                    bf16x8 wf = *(bf16x8*)(ldsW + d * LR + ((kt * 32 + q * 8) ^ (f << 3)));
#pragma unroll
                    for (int mt = 0; mt < 2; ++mt)
                        Y[mt][nd] = MFMA16(af[mt], wf, Y[mt][nd]);
                }
            }
        }

        if (pass == 0) {
            // o2 (=Y, C-layout) -> myP plain [t_local][d] (wave-private), then
            // X2-frags = 2*Q - o2 in B-frag layout.
#pragma unroll
            for (int mt = 0; mt < 2; ++mt)
#pragma unroll
                for (int nd = 0; nd < 4; ++nd)
#pragma unroll
                    for (int r = 0; r < 4; ++r)
                        myP[(mt * 16 + q * 4 + r) * LR + l16 + nd * 16] = (__bf16)Y[mt][nd][r];
#pragma unroll
            for (int ni = 0; ni < 2; ++ni)
#pragma unroll
                for (int kt = 0; kt < 2; ++kt) {
                    bf16x8 of = *(bf16x8*)(myP + (ni * 16 + l16) * LR + kt * 32 + q * 8);
#pragma unroll
                    for (int j = 0; j < 8; ++j)
                        Xf[ni][kt][j] = (__bf16)(2.0f * (float)Xf[ni][kt][j] - (float)of[j]);
                }
#pragma unroll
            for (int mt = 0; mt < 2; ++mt)
#pragma unroll
                for (int nd = 0; nd < 4; ++nd) Y[mt][nd] = zero4;
        } else {
            // out[b][t][h][d] fp32
#pragma unroll
            for (int mt = 0; mt < 2; ++mt)
#pragma unroll
                for (int nd = 0; nd < 4; ++nd)
#pragma unroll
                    for (int r = 0; r < 4; ++r) {
                        const int t = t0 + myT + mt * 16 + q * 4 + r;
                        const int d = l16 + nd * 16;
                        out[(((size_t)b * S + t) * H + h) * D + d] = Y[mt][nd][r];
                    }
        }
    }
}

extern "C" void kernel_launch(void* const* d_in, const int* in_sizes, int n_in,
                              void* d_out, int out_size, void* d_ws, size_t ws_size,
                              hipStream_t stream)
{
    const float* qkv = (const float*)d_in[0];
    float* out = (float*)d_out;
    dim3 grid(S / BM, 2 * H);   // 16 t-blocks x 32 (b,h)
    ttt_kernel<<<grid, 256, 0, stream>>>(qkv, out);
}

// Round 3
// 204.360 us; speedup vs baseline: 1.0983x; 1.0654x over previous
//
#include <hip/hip_runtime.h>
#include <hip/hip_bf16.h>

// out = tril((2Q - tril(QK^T)K) K^T) V per (b,h): two fused causal passes of
// Y = tril(X K^T) W  (pass0: X=Q,W=K -> o2; pass1: X=2Q-o2, W=V).
// R3: BM=64 -> 1024 WGs (16 waves/CU), corrected conflict-free swizzles:
//   ldsW col = s ^ (d&56); P-region col = (s + 8*l16) & 63.
// bf16 MFMA 16x16x32, fp32 accum.

typedef __bf16 bf16x8 __attribute__((ext_vector_type(8)));
typedef __bf16 bf16x4 __attribute__((ext_vector_type(4)));
typedef __bf16 bf16x2 __attribute__((ext_vector_type(2)));
typedef float  f32x4  __attribute__((ext_vector_type(4)));

#define MFMA16(a, b, c) __builtin_amdgcn_mfma_f32_16x16x32_bf16((a), (b), (c), 0, 0, 0)

static constexpr int S  = 2048;
static constexpr int H  = 16;
static constexpr int D  = 64;
static constexpr int RS = 3 * H * D;   // 3072 floats between consecutive s rows
static constexpr int BM = 64;          // query rows per workgroup (16/wave)
static constexpr int BN = 64;          // key rows per iteration
static constexpr int LR = 72;          // row stride (u16): 64 + 8

__global__ __launch_bounds__(256, 4)
void ttt_kernel(const float* __restrict__ qkv, float* __restrict__ out)
{
    __shared__ __bf16 ldsP[BM * LR];   // Q staging, then per-wave P / o2 regions
    __shared__ __bf16 ldsK[BN * LR];   // K tile row-major [s][d]
    __shared__ __bf16 ldsW[D  * LR];   // W^T [d][s ^ (d&56)]

    const int tid  = threadIdx.x;
    const int wv   = tid >> 6;
    const int lane = tid & 63;
    const int q    = lane >> 4;        // quad 0..3
    const int l16  = lane & 15;

    // XCD-pinned decode: blocks i = 0..1023; XCD ~ i%8; same bh stays on one XCD.
    const int i  = (int)blockIdx.x;
    const int bh = (i & 7) + 8 * (i >> 8);
    const int ti = 31 - ((i >> 3) & 31);     // heavy blocks dispatch first
    const int b  = bh >> 4;
    const int h  = bh & 15;
    const int t0 = ti * BM;
    const int nSB = ti + 1;

    const float* baseQ = qkv + (size_t)b * S * RS + h * D;
    const float* baseK = baseQ + H * D;
    const float* baseV = baseQ + 2 * H * D;

    // staging coords: thread owns rows r2,r2+1 cols cb..cb+7 of a 64x64 tile
    const int r2 = (tid >> 3) * 2;
    const int cb = (tid & 7) * 8;

    // ---- stage Q rows [t0,t0+64) -> ldsP row-major [t][d] ----
    {
        const int r   = tid >> 2;
        const int cbq = (tid & 3) * 16;
        const float* p = baseQ + (size_t)(t0 + r) * RS + cbq;
        __bf16* dst = ldsP + r * LR + cbq;
#pragma unroll
        for (int u = 0; u < 2; ++u) {
            f32x4 f0 = *(const f32x4*)(p + u * 8);
            f32x4 f1 = *(const f32x4*)(p + u * 8 + 4);
            bf16x8 w;
#pragma unroll
            for (int j = 0; j < 4; ++j) { w[j] = (__bf16)f0[j]; w[4 + j] = (__bf16)f1[j]; }
            *(bf16x8*)(dst + u * 8) = w;
        }
    }

    f32x4 pk[4], pv[4];   // prefetch regs: [0..1]=row r2, [2..3]=row r2+1
    auto loadT = [&](f32x4* dst, const float* base, int s0) {
        const float* p = base + (size_t)(s0 + r2) * RS + cb;
        dst[0] = *(const f32x4*)(p);
        dst[1] = *(const f32x4*)(p + 4);
        dst[2] = *(const f32x4*)(p + RS);
        dst[3] = *(const f32x4*)(p + RS + 4);
    };
    loadT(pk, baseK, 0);

    __syncthreads();   // Q staged

    // ---- hoist X B-frags: lane holds X[t=l16][d=kt*32+q*8+j] ----
    const int myT = wv * 16;
    bf16x8 Xf[2];
#pragma unroll
    for (int kt = 0; kt < 2; ++kt)
        Xf[kt] = *(bf16x8*)(ldsP + (myT + l16) * LR + kt * 32 + q * 8);

    __bf16* myP = ldsP + myT * LR;      // wave-private [16][LR]
    const int rot = 8 * l16;            // P-region rotation

    const f32x4 zero4 = {0.f, 0.f, 0.f, 0.f};
    f32x4 Y[4];
#pragma unroll
    for (int nd = 0; nd < 4; ++nd) Y[nd] = zero4;

    for (int pass = 0; pass < 2; ++pass) {
        for (int sb = 0; sb < nSB; ++sb) {
            __syncthreads();   // prior iter's ldsK/ldsW reads done
            // ---- commit prefetched tile to LDS ----
            {
                bf16x8 w0, w1;
#pragma unroll
                for (int j = 0; j < 4; ++j) {
                    w0[j] = (__bf16)pk[0][j]; w0[4 + j] = (__bf16)pk[1][j];
                    w1[j] = (__bf16)pk[2][j]; w1[4 + j] = (__bf16)pk[3][j];
                }
                *(bf16x8*)(ldsK + r2 * LR + cb)       = w0;
                *(bf16x8*)(ldsK + (r2 + 1) * LR + cb) = w1;
                f32x4* src = (pass == 0) ? pk : pv;
#pragma unroll
                for (int j = 0; j < 8; ++j) {
                    const int d = cb + j;
                    bf16x2 w;
                    w[0] = (__bf16)((j < 4) ? src[0][j & 3] : src[1][j & 3]);
                    w[1] = (__bf16)((j < 4) ? src[2][j & 3] : src[3][j & 3]);
                    *(bf16x2*)(ldsW + d * LR + (r2 ^ (d & 56))) = w;
                }
            }
            __syncthreads();   // tile visible

            // ---- prefetch next tile (drains at next barrier, a full iter away) ----
            if (sb + 1 < nSB) {
                loadT(pk, baseK, (sb + 1) * BN);
                if (pass == 1) loadT(pv, baseV, (sb + 1) * BN);
            } else if (pass == 0) {
                loadT(pk, baseK, 0);
                loadT(pv, baseV, 0);
            }

            // ---- GEMM1-T: Pt[s][t] = sum_d K[s][d] X[t][d]  (A=K, B=X^T) ----
            f32x4 Pt[4];
#pragma unroll
            for (int mi = 0; mi < 4; ++mi) Pt[mi] = zero4;
#pragma unroll
            for (int kt = 0; kt < 2; ++kt) {
#pragma unroll
                for (int mi = 0; mi < 4; ++mi) {
                    bf16x8 kf = *(bf16x8*)(ldsK + (mi * 16 + l16) * LR + kt * 32 + q * 8);
                    Pt[mi] = MFMA16(kf, Xf[kt], Pt[mi]);
                }
            }

            // ---- mask + pack + b64 store: myP[t_local][(s + 8*l16)&63] ----
            {
                const int tg = t0 + myT + l16;
#pragma unroll
                for (int mi = 0; mi < 4; ++mi) {
                    const int sgB = sb * BN + mi * 16 + q * 4;
                    bf16x4 pw;
#pragma unroll
                    for (int r = 0; r < 4; ++r)
                        pw[r] = (__bf16)((sgB + r <= tg) ? Pt[mi][r] : 0.0f);
                    *(bf16x4*)(myP + l16 * LR + ((mi * 16 + q * 4 + rot) & 63)) = pw;
                }
            }

            // ---- GEMM2: Y[t][d] += sum_s P[t][s] W[s][d] ----
#pragma unroll
            for (int kt = 0; kt < 2; ++kt) {
                bf16x8 af = *(bf16x8*)(myP + l16 * LR + ((kt * 32 + q * 8 + rot) & 63));
#pragma unroll
                for (int nd = 0; nd < 4; ++nd) {
                    const int d = l16 + nd * 16;
                    bf16x8 wf = *(bf16x8*)(ldsW + d * LR + ((kt * 32 + q * 8) ^ (d & 56)));
                    Y[nd] = MFMA16(af, wf, Y[nd]);
                }
            }
        }

        if (pass == 0) {
            // o2 (=Y, C-layout) -> myP plain [t_local][d], then X2 = 2Q - o2 in frags
#pragma unroll
            for (int nd = 0; nd < 4; ++nd)
#pragma unroll
                for (int r = 0; r < 4; ++r)
                    myP[(q * 4 + r) * LR + l16 + nd * 16] = (__bf16)Y[nd][r];
#pragma unroll
            for (int kt = 0; kt < 2; ++kt) {
                bf16x8 of = *(bf16x8*)(myP + l16 * LR + kt * 32 + q * 8);
#pragma unroll
                for (int j = 0; j < 8; ++j)
                    Xf[kt][j] = (__bf16)(2.0f * (float)Xf[kt][j] - (float)of[j]);
            }
#pragma unroll
            for (int nd = 0; nd < 4; ++nd) Y[nd] = zero4;
        } else {
            // out[b][t][h][d] fp32
#pragma unroll
            for (int nd = 0; nd < 4; ++nd)
#pragma unroll
                for (int r = 0; r < 4; ++r) {
                    const int t = t0 + myT + q * 4 + r;
                    const int d = l16 + nd * 16;
                    out[(((size_t)b * S + t) * H + h) * D + d] = Y[nd][r];
                }
        }
    }
}

extern "C" void kernel_launch(void* const* d_in, const int* in_sizes, int n_in,
                              void* d_out, int out_size, void* d_ws, size_t ws_size,
                              hipStream_t stream)
{
    const float* qkv = (const float*)d_in[0];
    float* out = (float*)d_out;
    ttt_kernel<<<dim3(1024), 256, 0, stream>>>(qkv, out);   // 32 ti x 32 bh
}

// Round 4
// 176.648 us; speedup vs baseline: 1.2707x; 1.1569x over previous
//
#include <hip/hip_runtime.h>
#include <hip/hip_bf16.h>

// out = tril((2Q - tril(QK^T)K) K^T) V per (b,h): two fused causal passes of
// Y = tril(X K^T) W  (pass0: X=Q,W=K -> o2; pass1: X=2Q-o2, W=V).
// R4: paired-strip workgroups. WG = pair (p, 31-p) of 64-row t-strips sharing
// the staged K/W tiles -> uniform work (33 strip-iters/pass), 2 MFMA per frag
// read. Grid 512 (= 2 WGs/CU exactly). bf16 MFMA 16x16x32, fp32 accum.

typedef __bf16 bf16x8 __attribute__((ext_vector_type(8)));
typedef __bf16 bf16x4 __attribute__((ext_vector_type(4)));
typedef __bf16 bf16x2 __attribute__((ext_vector_type(2)));
typedef float  f32x4  __attribute__((ext_vector_type(4)));

#define MFMA16(a, b, c) __builtin_amdgcn_mfma_f32_16x16x32_bf16((a), (b), (c), 0, 0, 0)

static constexpr int S  = 2048;
static constexpr int H  = 16;
static constexpr int D  = 64;
static constexpr int RS = 3 * H * D;   // 3072 floats between consecutive s rows
static constexpr int BN = 64;          // key rows per iteration
static constexpr int LR = 72;          // row stride (u16): 64 + 8

__global__ __launch_bounds__(256, 2)
void ttt_kernel(const float* __restrict__ qkv, float* __restrict__ out)
{
    __shared__ __bf16 ldsS[128 * LR];  // Q staging -> per-wave P/o2 scratch
    __shared__ __bf16 ldsK[BN * LR];   // K tile row-major [s][d]
    __shared__ __bf16 ldsW[D  * LR];   // W^T [d][s ^ (d&56)]

    const int tid  = threadIdx.x;
    const int wv   = tid >> 6;
    const int lane = tid & 63;
    const int q    = lane >> 4;        // quad 0..3
    const int l16  = lane & 15;

    // i bits: [8:7]=bh-high, [6:3]=pair, [2:0]=bh-low  (same bh -> same XCD)
    const int i  = (int)blockIdx.x;
    const int p  = (i >> 3) & 15;
    const int bh = (i & 7) + 8 * (i >> 7);
    const int b  = bh >> 4;
    const int h  = bh & 15;
    const int tA = 64 * p;             // light strip
    const int tB = 64 * (31 - p);      // heavy strip
    const int nA = p + 1;              // s-blocks for strip A
    const int nB = 32 - p;             // s-blocks for strip B (>= nA always)

    const float* baseQ = qkv + (size_t)b * S * RS + h * D;
    const float* baseK = baseQ + H * D;
    const float* baseV = baseQ + 2 * H * D;

    // staging coords: thread owns rows r2,r2+1 cols cb..cb+7 of a 64x64 tile
    const int r2 = (tid >> 3) * 2;
    const int cb = (tid & 7) * 8;

    // ---- stage Q for both strips (128 rows) -> ldsS row-major [t][d] ----
    {
        const int r   = tid >> 1;
        const int gr  = (r < 64) ? (tA + r) : (tB + r - 64);
        const int cbq = (tid & 1) * 32;
        const float* pq = baseQ + (size_t)gr * RS + cbq;
        __bf16* dst = ldsS + r * LR + cbq;
#pragma unroll
        for (int u = 0; u < 4; ++u) {
            f32x4 f0 = *(const f32x4*)(pq + u * 8);
            f32x4 f1 = *(const f32x4*)(pq + u * 8 + 4);
            bf16x8 w;
#pragma unroll
            for (int j = 0; j < 4; ++j) { w[j] = (__bf16)f0[j]; w[4 + j] = (__bf16)f1[j]; }
            *(bf16x8*)(dst + u * 8) = w;
        }
    }

    f32x4 pk[4], pv[4];   // prefetch regs: [0..1]=row r2, [2..3]=row r2+1
    auto loadT = [&](f32x4* dst, const float* base, int s0) {
        const float* pg = base + (size_t)(s0 + r2) * RS + cb;
        dst[0] = *(const f32x4*)(pg);
        dst[1] = *(const f32x4*)(pg + 4);
        dst[2] = *(const f32x4*)(pg + RS);
        dst[3] = *(const f32x4*)(pg + RS + 4);
    };
    loadT(pk, baseK, 0);

    __syncthreads();   // Q staged

    // ---- hoist X B-frags for both strips: lane holds X[t=l16][d=kt*32+q*8+j] ----
    bf16x8 Xf[2][2];   // [strip][kt]
    const int rowA = wv * 16;
    const int rowB = 64 + wv * 16;
#pragma unroll
    for (int kt = 0; kt < 2; ++kt) {
        Xf[0][kt] = *(bf16x8*)(ldsS + (rowA + l16) * LR + kt * 32 + q * 8);
        Xf[1][kt] = *(bf16x8*)(ldsS + (rowB + l16) * LR + kt * 32 + q * 8);
    }
    __bf16* sA = ldsS + rowA * LR;     // wave-private scratch, strip A (16 rows)
    __bf16* sB = ldsS + rowB * LR;     // wave-private scratch, strip B
    const int rot = 8 * l16;           // P-region rotation swizzle

    const f32x4 zero4 = {0.f, 0.f, 0.f, 0.f};
    f32x4 Y[2][4];                     // [strip][nd]
#pragma unroll
    for (int st = 0; st < 2; ++st)
#pragma unroll
        for (int nd = 0; nd < 4; ++nd) Y[st][nd] = zero4;

    for (int pass = 0; pass < 2; ++pass) {
        for (int sb = 0; sb < nB; ++sb) {
            const bool actA = (sb < nA);           // block-uniform branch
            __syncthreads();                       // prior iter's tile reads done
            // ---- commit prefetched tile to LDS ----
            {
                bf16x8 w0, w1;
#pragma unroll
                for (int j = 0; j < 4; ++j) {
                    w0[j] = (__bf16)pk[0][j]; w0[4 + j] = (__bf16)pk[1][j];
                    w1[j] = (__bf16)pk[2][j]; w1[4 + j] = (__bf16)pk[3][j];
                }
                *(bf16x8*)(ldsK + r2 * LR + cb)       = w0;
                *(bf16x8*)(ldsK + (r2 + 1) * LR + cb) = w1;
                f32x4* src = (pass == 0) ? pk : pv;
#pragma unroll
                for (int j = 0; j < 8; ++j) {
                    const int d = cb + j;
                    bf16x2 w;
                    w[0] = (__bf16)((j < 4) ? src[0][j & 3] : src[1][j & 3]);
                    w[1] = (__bf16)((j < 4) ? src[2][j & 3] : src[3][j & 3]);
                    *(bf16x2*)(ldsW + d * LR + (r2 ^ (d & 56))) = w;
                }
            }
            __syncthreads();                       // tile visible

            // ---- prefetch next tile (drains a full GEMM-phase later) ----
            if (sb + 1 < nB) {
                loadT(pk, baseK, (sb + 1) * BN);
                if (pass == 1) loadT(pv, baseV, (sb + 1) * BN);
            } else if (pass == 0) {
                loadT(pk, baseK, 0);
                loadT(pv, baseV, 0);
            }

            // ---- GEMM1-T both strips: Pt[s][t] = sum_d K[s][d] X[t][d] ----
            f32x4 PtA[4], PtB[4];
#pragma unroll
            for (int mi = 0; mi < 4; ++mi) { PtA[mi] = zero4; PtB[mi] = zero4; }
#pragma unroll
            for (int kt = 0; kt < 2; ++kt) {
#pragma unroll
                for (int mi = 0; mi < 4; ++mi) {
                    bf16x8 kf = *(bf16x8*)(ldsK + (mi * 16 + l16) * LR + kt * 32 + q * 8);
                    PtB[mi] = MFMA16(kf, Xf[1][kt], PtB[mi]);
                    if (actA) PtA[mi] = MFMA16(kf, Xf[0][kt], PtA[mi]);
                }
            }

            // ---- mask + pack + b64 store: s?[t_local][(s + 8*l16)&63] ----
            {
                const int tgB = tB + wv * 16 + l16;
                const int tgA = tA + wv * 16 + l16;
#pragma unroll
                for (int mi = 0; mi < 4; ++mi) {
                    const int sg0 = sb * BN + mi * 16 + q * 4;
                    bf16x4 pwB;
#pragma unroll
                    for (int r = 0; r < 4; ++r)
                        pwB[r] = (__bf16)((sg0 + r <= tgB) ? PtB[mi][r] : 0.0f);
                    *(bf16x4*)(sB + l16 * LR + ((mi * 16 + q * 4 + rot) & 63)) = pwB;
                    if (actA) {
                        bf16x4 pwA;
#pragma unroll
                        for (int r = 0; r < 4; ++r)
                            pwA[r] = (__bf16)((sg0 + r <= tgA) ? PtA[mi][r] : 0.0f);
                        *(bf16x4*)(sA + l16 * LR + ((mi * 16 + q * 4 + rot) & 63)) = pwA;
                    }
                }
            }

            // ---- GEMM2 both strips: Y[t][d] += sum_s P[t][s] W[s][d] ----
#pragma unroll
            for (int kt = 0; kt < 2; ++kt) {
                bf16x8 afB = *(bf16x8*)(sB + l16 * LR + ((kt * 32 + q * 8 + rot) & 63));
                bf16x8 afA;
                if (actA) afA = *(bf16x8*)(sA + l16 * LR + ((kt * 32 + q * 8 + rot) & 63));
#pragma unroll
                for (int nd = 0; nd < 4; ++nd) {
                    const int d = l16 + nd * 16;
                    bf16x8 wf = *(bf16x8*)(ldsW + d * LR + ((kt * 32 + q * 8) ^ (d & 56)));
                    Y[1][nd] = MFMA16(afB, wf, Y[1][nd]);
                    if (actA) Y[0][nd] = MFMA16(afA, wf, Y[0][nd]);
                }
            }
        }

        if (pass == 0) {
            // per strip: o2 (C-layout) -> scratch plain [t][d], reread as frags,
            // Xf = 2Q - o2; then reset Y.
#pragma unroll
            for (int st = 0; st < 2; ++st) {
                __bf16* sc = (st == 0) ? sA : sB;
#pragma unroll
                for (int nd = 0; nd < 4; ++nd)
#pragma unroll
                    for (int r = 0; r < 4; ++r)
                        sc[(q * 4 + r) * LR + l16 + nd * 16] = (__bf16)Y[st][nd][r];
#pragma unroll
                for (int kt = 0; kt < 2; ++kt) {
                    bf16x8 of = *(bf16x8*)(sc + l16 * LR + kt * 32 + q * 8);
#pragma unroll
                    for (int j = 0; j < 8; ++j)
                        Xf[st][kt][j] = (__bf16)(2.0f * (float)Xf[st][kt][j] - (float)of[j]);
                }
#pragma unroll
                for (int nd = 0; nd < 4; ++nd) Y[st][nd] = zero4;
            }
        } else {
            // out[b][t][h][d] fp32, both strips
#pragma unroll
            for (int st = 0; st < 2; ++st) {
                const int tb = (st == 0) ? tA : tB;
#pragma unroll
                for (int nd = 0; nd < 4; ++nd)
#pragma unroll
                    for (int r = 0; r < 4; ++r) {
                        const int t = tb + wv * 16 + q * 4 + r;
                        const int d = l16 + nd * 16;
                        out[(((size_t)b * S + t) * H + h) * D + d] = Y[st][nd][r];
                    }
            }
        }
    }
}

extern "C" void kernel_launch(void* const* d_in, const int* in_sizes, int n_in,
                              void* d_out, int out_size, void* d_ws, size_t ws_size,
                              hipStream_t stream)
{
    const float* qkv = (const float*)d_in[0];
    float* out = (float*)d_out;
    ttt_kernel<<<dim3(512), 256, 0, stream>>>(qkv, out);   // 16 pairs x 32 bh
}